// Round 16
// baseline (290.419 us; speedup 1.0000x reference)
//
#include <hip/hip_runtime.h>
#include <hip/hip_bf16.h>
#include <hip/hip_fp16.h>

#define NB 4
#define LL 4096
#define SS 4096
#define CC 128
#define NSTRIP 256   // LL / 16

typedef unsigned short u16;
typedef _Float16 f16;
typedef __attribute__((ext_vector_type(8))) short  short8;
typedef __attribute__((ext_vector_type(8))) f16    f16x8;
typedef __attribute__((ext_vector_type(4))) float  f32x4;
typedef __attribute__((ext_vector_type(4))) u16    u16x4;

// ---------- helpers ----------
__device__ __forceinline__ u16 f2bf(float f) {
  unsigned u = __float_as_uint(f);
  return (u16)((u + 0x7FFFu + ((u >> 16) & 1u)) >> 16);   // RNE, inputs finite
}

__device__ __forceinline__ void gload_lds16(const void* g, void* l) {
  __builtin_amdgcn_global_load_lds(
      (const __attribute__((address_space(1))) unsigned*)g,
      (__attribute__((address_space(3))) unsigned*)l, 16, 0, 0);
}

template <int NW>
__device__ __forceinline__ float block_sum(float v, float* red, int t) {
#pragma unroll
  for (int m = 1; m < 64; m <<= 1) v += __shfl_xor(v, m, 64);
  if ((t & 63) == 0) red[t >> 6] = v;
  __syncthreads();
  float s = 0.f;
#pragma unroll
  for (int w = 0; w < NW; ++w) s += red[w];
  __syncthreads();
  return s;
}

// ---------- fp32 -> bf16 conversion (+ zero the scalar accumulators) ----------
__global__ __launch_bounds__(256) void k_convert(const float* __restrict__ f0,
                                                 const float* __restrict__ f1,
                                                 u16* __restrict__ b0,
                                                 u16* __restrict__ b1,
                                                 float* __restrict__ scal) {
  const int i = blockIdx.x * 256 + threadIdx.x;
  if (blockIdx.x == 0 && threadIdx.x < 64) scal[threadIdx.x] = 0.f;
  const int n = NB * LL * CC / 4;
  if (i >= n) return;
  f32x4 x = __builtin_nontemporal_load((const f32x4*)f0 + i);
  f32x4 y = __builtin_nontemporal_load((const f32x4*)f1 + i);
  u16x4 a, c;
  a[0] = f2bf(x[0]); a[1] = f2bf(x[1]); a[2] = f2bf(x[2]); a[3] = f2bf(x[3]);
  c[0] = f2bf(y[0]); c[1] = f2bf(y[1]); c[2] = f2bf(y[2]); c[3] = f2bf(y[3]);
  ((u16x4*)b0)[i] = a;
  ((u16x4*)b1)[i] = c;
}

// ---------- bf16 MFMA GEMM: E = exp(f0.f1^T/128) f16, partial rowsums (no atomics) ----------
__global__ __launch_bounds__(256) void k_gemm(const u16* __restrict__ b0,
                                              const u16* __restrict__ b1,
                                              f16* __restrict__ E,
                                              float* __restrict__ rowpart) {
  __shared__ u16 smem[2 * 128 * 128];
  u16* lA = smem;
  u16* lB = smem + 128 * 128;
  const int bx = blockIdx.x, by = blockIdx.y, bz = blockIdx.z;
  const int tid = threadIdx.x;
  const int lane = tid & 63, wave = tid >> 6;

  const u16* gA = b0 + (size_t)bz * LL * CC + (size_t)by * 128 * CC;
  const u16* gB = b1 + (size_t)bz * SS * CC + (size_t)bx * 128 * CC;

#pragma unroll
  for (int i = 0; i < 8; ++i) {
    const int c = i * 256 + tid;
    const int row = c >> 4;
    const int slot = c & 15;
    const int kchunk = slot ^ (row & 7);
    const size_t soff = (size_t)row * CC + kchunk * 8;
    const int ldsoff = (i * 256 + wave * 64) * 16;
    gload_lds16(gA + soff, (char*)lA + ldsoff);
    gload_lds16(gB + soff, (char*)lB + ldsoff);
  }
  __syncthreads();

  const int wr = wave >> 1, wc = wave & 1;
  f32x4 acc[4][4];
#pragma unroll
  for (int i = 0; i < 4; ++i)
#pragma unroll
    for (int j = 0; j < 4; ++j) acc[i][j] = (f32x4){0.f, 0.f, 0.f, 0.f};

#pragma unroll
  for (int ks = 0; ks < 4; ++ks) {
    short8 af[4], bfr[4];
#pragma unroll
    for (int mi = 0; mi < 4; ++mi) {
      const int row = wr * 64 + mi * 16 + (lane & 15);
      const int kc = ks * 4 + (lane >> 4);
      af[mi] = *(const short8*)&lA[row * 128 + (kc ^ (row & 7)) * 8];
    }
#pragma unroll
    for (int ni = 0; ni < 4; ++ni) {
      const int row = wc * 64 + ni * 16 + (lane & 15);
      const int kc = ks * 4 + (lane >> 4);
      bfr[ni] = *(const short8*)&lB[row * 128 + (kc ^ (row & 7)) * 8];
    }
#pragma unroll
    for (int mi = 0; mi < 4; ++mi)
#pragma unroll
      for (int ni = 0; ni < 4; ++ni)
        acc[mi][ni] = __builtin_amdgcn_mfma_f32_16x16x32_bf16(af[mi], bfr[ni], acc[mi][ni], 0, 0, 0);
  }

  __syncthreads();                       // all LDS fragment reads done
  f16* st = (f16*)smem;                  // staging, row stride 136 f16 (16B-aligned rows)
  const float scale = 1.0f / 128.0f;
  // rowpart slice: [bz][bx*2+wc][row]  (each wave's 64-col half-sum, no races)
  float* rp = rowpart + ((size_t)bz * 64 + bx * 2 + wc) * LL + by * 128;
#pragma unroll
  for (int mi = 0; mi < 4; ++mi) {
    float rs[4] = {0.f, 0.f, 0.f, 0.f};
    const int lr0 = wr * 64 + mi * 16 + (lane >> 4) * 4;
#pragma unroll
    for (int ni = 0; ni < 4; ++ni) {
      const int lc = wc * 64 + ni * 16 + (lane & 15);
      f32x4 a = acc[mi][ni];
#pragma unroll
      for (int r = 0; r < 4; ++r) {
        const f16 eh = (f16)__expf(a[r] * scale);
        st[(lr0 + r) * 136 + lc] = eh;
        rs[r] += (float)eh;
      }
    }
#pragma unroll
    for (int m = 1; m < 16; m <<= 1)
#pragma unroll
      for (int r = 0; r < 4; ++r) rs[r] += __shfl_xor(rs[r], m, 64);
    if ((lane & 15) == 0) {
#pragma unroll
      for (int r = 0; r < 4; ++r) rp[lr0 + r] = rs[r];
    }
  }
  __syncthreads();
  const size_t ebase = (size_t)bz * LL * SS + (size_t)(by * 128) * SS + (size_t)(bx * 128);
#pragma unroll
  for (int i = 0; i < 8; ++i) {
    const int c = i * 256 + tid;
    const int row = c >> 4, c16 = c & 15;
    f16x8 vv = *(const f16x8*)&st[row * 136 + c16 * 8];
    *(f16x8*)&E[ebase + (size_t)row * SS + c16 * 8] = vv;
  }
}

// ---------- column pass IT=1..3: (IT>1: row-dots -> eu), colpart[strip] = sum(eu*E)
//            IT>1 holds the 16x16 E sub-strip in registers: ONE E read total.
//            colpart stored as f16 (halves its traffic; 5e-4 rel err is benign) ----------
template <int IT>
__global__ __launch_bounds__(256, 2) void k_colpass(const f16* __restrict__ E,
                                                    const float* __restrict__ rowpart,
                                                    const float* __restrict__ evprev,
                                                    f16* __restrict__ colpart,
                                                    float* __restrict__ eu3g,
                                                    float* __restrict__ scal,
                                                    const float* __restrict__ alpha_p) {
  __shared__ float lds_red[4][16];
  __shared__ float eu_lds[16];
  const int b = blockIdx.y, strip = blockIdx.x;
  const int t = threadIdx.x, lane = t & 63, wave = t >> 6;
  const float alpha = *alpha_p;
  const float EA = __expf(alpha), HE = 0.5f * __expf(-alpha);
  const float enorm = 1.0f / 8192.0f;
  const float EU1BIN = HE / 4097.0f;

  const f16* Eb = E + (size_t)b * LL * SS + (size_t)strip * 16 * SS;
  const int cA = t * 8, cB = 2048 + t * 8;
  f16* co = colpart + ((size_t)b * NSTRIP + strip) * SS;

  if (IT == 1) {
    // eu1 for this strip from rowpart: 16 rows x 64 partials (wave 0 only)
    if (wave == 0) {
      const int r = lane & 15, g = lane >> 4;       // 4 groups x 16 rows
      float s = 0.f;
      const float* rp = rowpart + (size_t)b * 64 * LL + strip * 16 + r;
#pragma unroll
      for (int j = 0; j < 16; ++j) s += rp[(size_t)(g * 16 + j) * LL];
      s += __shfl_xor(s, 16, 64);
      s += __shfl_xor(s, 32, 64);
      float eu = 0.f;
      if (lane < 16) {
        eu = enorm / (s + EA);
        eu_lds[lane] = eu;
      }
      // sa1 partial (lanes 0-15 hold eu)
      float es = eu;
#pragma unroll
      for (int m = 1; m < 16; m <<= 1) es += __shfl_xor(es, m, 64);
      if (lane == 0) atomicAdd(&scal[b * 8 + 0], es);
    }
    __syncthreads();
    float eur[16];
#pragma unroll
    for (int r = 0; r < 16; ++r) eur[r] = eu_lds[r];
    float accA[8], accB[8];
#pragma unroll
    for (int e = 0; e < 8; ++e) { accA[e] = 0.f; accB[e] = 0.f; }
#pragma unroll
    for (int r = 0; r < 16; ++r) {
      const f16x8 hA = *(const f16x8*)(Eb + (size_t)r * SS + cA);
      const f16x8 hB = *(const f16x8*)(Eb + (size_t)r * SS + cB);
#pragma unroll
      for (int e = 0; e < 8; ++e) { accA[e] += eur[r] * (float)hA[e]; accB[e] += eur[r] * (float)hB[e]; }
    }
    f16x8 sA, sB;
#pragma unroll
    for (int e = 0; e < 8; ++e) { sA[e] = (f16)accA[e]; sB[e] = (f16)accB[e]; }
    *(f16x8*)&co[cA] = sA;
    *(f16x8*)&co[cB] = sB;
    return;
  }

  // ---- IT >= 2: bin-chain scalars ----
  const float sa1 = scal[b * 8 + 0];
  const float ev1bin = HE / (sa1 + EU1BIN);
  float btu;
  if (IT == 2) {
    btu = EA * ev1bin;
  } else {
    const float sev1 = scal[b * 8 + 1];
    const float eu2bin = HE / (sev1 + ev1bin);
    const float s2 = scal[b * 8 + 2];
    const float ev2bin = HE / (s2 + eu2bin);
    btu = EA * ev2bin;
  }
  const float* evb = evprev + (size_t)b * SS;
  const f32x4 evA0 = *(const f32x4*)&evb[cA];
  const f32x4 evA1 = *(const f32x4*)&evb[cA + 4];
  const f32x4 evB0 = *(const f32x4*)&evb[cB];
  const f32x4 evB1 = *(const f32x4*)&evb[cB + 4];

  // phase A: load E sub-strip into registers + per-thread partial row-dots
  f16x8 eAr[16], eBr[16];
  float partial[16];
#pragma unroll
  for (int r = 0; r < 16; ++r) {
    eAr[r] = *(const f16x8*)(Eb + (size_t)r * SS + cA);
    eBr[r] = *(const f16x8*)(Eb + (size_t)r * SS + cB);
    float d = 0.f;
#pragma unroll
    for (int e = 0; e < 4; ++e) d += (float)eAr[r][e] * evA0[e];
#pragma unroll
    for (int e = 0; e < 4; ++e) d += (float)eAr[r][4 + e] * evA1[e];
#pragma unroll
    for (int e = 0; e < 4; ++e) d += (float)eBr[r][e] * evB0[e];
#pragma unroll
    for (int e = 0; e < 4; ++e) d += (float)eBr[r][4 + e] * evB1[e];
    partial[r] = d;
  }

  // phase B: block reduction of 16 row-dots
#pragma unroll
  for (int m = 1; m < 64; m <<= 1)
#pragma unroll
    for (int r = 0; r < 16; ++r) partial[r] += __shfl_xor(partial[r], m, 64);
  if (lane == 0) {
#pragma unroll
    for (int r = 0; r < 16; ++r) lds_red[wave][r] = partial[r];
  }
  __syncthreads();
  if (t < 16) {
    const float rd = lds_red[0][t] + lds_red[1][t] + lds_red[2][t] + lds_red[3][t];
    const float eu = enorm / (rd + btu);
    eu_lds[t] = eu;
    if (IT == 3) eu3g[(size_t)b * LL + strip * 16 + t] = eu;
  }
  __syncthreads();
  if (IT == 2 && t == 0) {
    float s = 0.f;
#pragma unroll
    for (int r = 0; r < 16; ++r) s += eu_lds[r];
    atomicAdd(&scal[b * 8 + 2], s);
  }
  float eur[16];
#pragma unroll
  for (int r = 0; r < 16; ++r) eur[r] = eu_lds[r];

  // phase C: colpart from REGISTER-held E (no second memory read)
  float accA[8], accB[8];
#pragma unroll
  for (int e = 0; e < 8; ++e) { accA[e] = 0.f; accB[e] = 0.f; }
#pragma unroll
  for (int r = 0; r < 16; ++r) {
#pragma unroll
    for (int e = 0; e < 8; ++e) { accA[e] += eur[r] * (float)eAr[r][e]; accB[e] += eur[r] * (float)eBr[r][e]; }
  }
  f16x8 sA, sB;
#pragma unroll
  for (int e = 0; e < 8; ++e) { sA[e] = (f16)accA[e]; sB[e] = (f16)accB[e]; }
  *(f16x8*)&co[cA] = sA;
  *(f16x8*)&co[cB] = sB;
}

// ---------- reduce colpart (f16) -> ev_IT (+ sev atomic) ----------
template <int IT>
__global__ __launch_bounds__(256) void k_redcol(const f16* __restrict__ colpart,
                                                float* __restrict__ evout,
                                                float* __restrict__ scal,
                                                const float* __restrict__ alpha_p) {
  __shared__ float red[4];
  const int b = blockIdx.y, t = threadIdx.x;
  const int c = blockIdx.x * 256 + t;
  const float alpha = *alpha_p;
  const float EA = __expf(alpha), HE = 0.5f * __expf(-alpha);
  const float enorm = 1.0f / 8192.0f;
  const float EU1BIN = HE / 4097.0f, BTV1 = 0.5f / 4097.0f;

  float s = 0.f;
  const f16* cp = colpart + (size_t)b * NSTRIP * SS + c;
#pragma unroll 8
  for (int st = 0; st < NSTRIP; ++st) s += (float)cp[(size_t)st * SS];

  float btv;
  if (IT == 1) {
    btv = BTV1;
  } else {
    const float sa1 = scal[b * 8 + 0];
    const float ev1bin = HE / (sa1 + EU1BIN);
    const float sev1 = scal[b * 8 + 1];
    const float eu2bin = HE / (sev1 + ev1bin);
    if (IT == 2) {
      btv = EA * eu2bin;
    } else {
      const float s2 = scal[b * 8 + 2];
      const float ev2bin = HE / (s2 + eu2bin);
      const float sev2 = scal[b * 8 + 3];
      const float eu3bin = HE / (sev2 + ev2bin);
      btv = EA * eu3bin;
    }
  }
  const float ev = enorm / (s + btv);
  evout[(size_t)b * SS + c] = ev;
  if (IT < 3) {
    const float bs = block_sum<4>(ev, red, t);
    if (t == 0) atomicAdd(&scal[b * 8 + (IT == 1 ? 1 : 3)], bs);
  }
}

// ---------- final: out = E * eu3[l] * ev3[s] * 8192 ----------
// Column-split: each block does 16 rows x 2048 cols -> 2048 blocks, ~40 VGPR.
__global__ __launch_bounds__(256) void k_finalize(const f16* __restrict__ E,
                                                  float* __restrict__ out,
                                                  const float* __restrict__ eu3g,
                                                  const float* __restrict__ ev3g) {
  __shared__ float eu_s[16];
  const int b = blockIdx.y;
  const int rb = blockIdx.x >> 1, half = blockIdx.x & 1;
  const int t = threadIdx.x, lane = t & 63, wave = t >> 6;
  if (t < 16) eu_s[t] = eu3g[(size_t)b * LL + rb * 16 + t] * 8192.0f;

  const float* evb = ev3g + (size_t)b * SS + half * 2048;
  f32x4 evr[8];
#pragma unroll
  for (int it = 0; it < 4; ++it) {
    const int base = (it * 64 + lane) * 8;
    evr[it * 2] = *(const f32x4*)&evb[base];
    evr[it * 2 + 1] = *(const f32x4*)&evb[base + 4];
  }
  __syncthreads();

  const size_t rbase = (size_t)b * LL * SS + (size_t)(rb * 16) * SS + half * 2048;
#pragma unroll
  for (int rr = 0; rr < 4; ++rr) {
    const int rloc = wave * 4 + rr;
    const float a = eu_s[rloc];
    const f16x8* rowp = (const f16x8*)(E + rbase + (size_t)rloc * SS);
    f32x4* orow = (f32x4*)(out + rbase + (size_t)rloc * SS);
#pragma unroll
    for (int it = 0; it < 4; ++it) {
      const f16x8 h = rowp[it * 64 + lane];
      f32x4 o0, o1;
#pragma unroll
      for (int e = 0; e < 4; ++e) o0[e] = (float)h[e] * a * evr[it * 2][e];
#pragma unroll
      for (int e = 0; e < 4; ++e) o1[e] = (float)h[4 + e] * a * evr[it * 2 + 1][e];
      orow[2 * (it * 64 + lane)] = o0;
      orow[2 * (it * 64 + lane) + 1] = o1;
    }
  }
}

// ---------- launch ----------
extern "C" void kernel_launch(void* const* d_in, const int* in_sizes, int n_in,
                              void* d_out, int out_size, void* d_ws, size_t ws_size,
                              hipStream_t stream) {
  const float* f0 = (const float*)d_in[0];
  const float* f1 = (const float*)d_in[1];
  const float* alpha_p = (const float*)d_in[2];
  float* out = (float*)d_out;

  char* ws = (char*)d_ws;
  size_t off = (size_t)NB * LL * SS * 2;                    // E: 128 MiB
  f16* E = (f16*)ws;
  u16* b0 = (u16*)(ws + off);      off += (size_t)NB * LL * CC * 2;
  u16* b1 = (u16*)(ws + off);      off += (size_t)NB * SS * CC * 2;
  float* rowpart = (float*)(ws + off); off += (size_t)NB * 64 * LL * 4;     // 4 MiB
  f16* colpart = (f16*)(ws + off);     off += (size_t)NB * NSTRIP * SS * 2; // 8 MiB
  float* eu3g = (float*)(ws + off);    off += (size_t)NB * LL * 4;
  float* ev1g = (float*)(ws + off);    off += (size_t)NB * SS * 4;
  float* ev2g = (float*)(ws + off);    off += (size_t)NB * SS * 4;
  float* ev3g = (float*)(ws + off);    off += (size_t)NB * SS * 4;
  float* scal = (float*)(ws + off);    off += 256;

  k_convert<<<2048, 256, 0, stream>>>(f0, f1, b0, b1, scal);
  k_gemm<<<dim3(SS / 128, LL / 128, NB), 256, 0, stream>>>(b0, b1, E, rowpart);

  k_colpass<1><<<dim3(NSTRIP, NB), 256, 0, stream>>>(E, rowpart, nullptr, colpart, eu3g, scal, alpha_p);
  k_redcol<1><<<dim3(16, NB), 256, 0, stream>>>(colpart, ev1g, scal, alpha_p);

  k_colpass<2><<<dim3(NSTRIP, NB), 256, 0, stream>>>(E, rowpart, ev1g, colpart, eu3g, scal, alpha_p);
  k_redcol<2><<<dim3(16, NB), 256, 0, stream>>>(colpart, ev2g, scal, alpha_p);

  k_colpass<3><<<dim3(NSTRIP, NB), 256, 0, stream>>>(E, rowpart, ev2g, colpart, eu3g, scal, alpha_p);
  k_redcol<3><<<dim3(16, NB), 256, 0, stream>>>(colpart, ev3g, scal, alpha_p);

  k_finalize<<<dim3(LL / 16 * 2, NB), 256, 0, stream>>>(E, out, eu3g, ev3g);
}

// Round 17
// 285.540 us; speedup vs baseline: 1.0171x; 1.0171x over previous
//
#include <hip/hip_runtime.h>
#include <hip/hip_bf16.h>
#include <hip/hip_fp16.h>

#define NB 4
#define LL 4096
#define SS 4096
#define CC 128
#define NSTRIP 256   // LL / 16

typedef unsigned short u16;
typedef _Float16 f16;
typedef __attribute__((ext_vector_type(8))) short  short8;
typedef __attribute__((ext_vector_type(8))) f16    f16x8;
typedef __attribute__((ext_vector_type(4))) float  f32x4;
typedef __attribute__((ext_vector_type(4))) u16    u16x4;

// ---------- helpers ----------
__device__ __forceinline__ u16 f2bf(float f) {
  unsigned u = __float_as_uint(f);
  return (u16)((u + 0x7FFFu + ((u >> 16) & 1u)) >> 16);   // RNE, inputs finite
}

__device__ __forceinline__ void gload_lds16(const void* g, void* l) {
  __builtin_amdgcn_global_load_lds(
      (const __attribute__((address_space(1))) unsigned*)g,
      (__attribute__((address_space(3))) unsigned*)l, 16, 0, 0);
}

template <int NW>
__device__ __forceinline__ float block_sum(float v, float* red, int t) {
#pragma unroll
  for (int m = 1; m < 64; m <<= 1) v += __shfl_xor(v, m, 64);
  if ((t & 63) == 0) red[t >> 6] = v;
  __syncthreads();
  float s = 0.f;
#pragma unroll
  for (int w = 0; w < NW; ++w) s += red[w];
  __syncthreads();
  return s;
}

// ---------- fp32 -> bf16 conversion (+ zero the scalar accumulators) ----------
__global__ __launch_bounds__(256) void k_convert(const float* __restrict__ f0,
                                                 const float* __restrict__ f1,
                                                 u16* __restrict__ b0,
                                                 u16* __restrict__ b1,
                                                 float* __restrict__ scal) {
  const int i = blockIdx.x * 256 + threadIdx.x;
  if (blockIdx.x == 0 && threadIdx.x < 64) scal[threadIdx.x] = 0.f;
  const int n = NB * LL * CC / 4;
  if (i >= n) return;
  f32x4 x = __builtin_nontemporal_load((const f32x4*)f0 + i);
  f32x4 y = __builtin_nontemporal_load((const f32x4*)f1 + i);
  u16x4 a, c;
  a[0] = f2bf(x[0]); a[1] = f2bf(x[1]); a[2] = f2bf(x[2]); a[3] = f2bf(x[3]);
  c[0] = f2bf(y[0]); c[1] = f2bf(y[1]); c[2] = f2bf(y[2]); c[3] = f2bf(y[3]);
  ((u16x4*)b0)[i] = a;
  ((u16x4*)b1)[i] = c;
}

// ---------- bf16 MFMA GEMM: E = exp(f0.f1^T/128) f16, partial rowsums (no atomics) ----------
__global__ __launch_bounds__(256) void k_gemm(const u16* __restrict__ b0,
                                              const u16* __restrict__ b1,
                                              f16* __restrict__ E,
                                              float* __restrict__ rowpart) {
  __shared__ u16 smem[2 * 128 * 128];
  u16* lA = smem;
  u16* lB = smem + 128 * 128;
  const int bx = blockIdx.x, by = blockIdx.y, bz = blockIdx.z;
  const int tid = threadIdx.x;
  const int lane = tid & 63, wave = tid >> 6;

  const u16* gA = b0 + (size_t)bz * LL * CC + (size_t)by * 128 * CC;
  const u16* gB = b1 + (size_t)bz * SS * CC + (size_t)bx * 128 * CC;

#pragma unroll
  for (int i = 0; i < 8; ++i) {
    const int c = i * 256 + tid;
    const int row = c >> 4;
    const int slot = c & 15;
    const int kchunk = slot ^ (row & 7);
    const size_t soff = (size_t)row * CC + kchunk * 8;
    const int ldsoff = (i * 256 + wave * 64) * 16;
    gload_lds16(gA + soff, (char*)lA + ldsoff);
    gload_lds16(gB + soff, (char*)lB + ldsoff);
  }
  __syncthreads();

  const int wr = wave >> 1, wc = wave & 1;
  f32x4 acc[4][4];
#pragma unroll
  for (int i = 0; i < 4; ++i)
#pragma unroll
    for (int j = 0; j < 4; ++j) acc[i][j] = (f32x4){0.f, 0.f, 0.f, 0.f};

#pragma unroll
  for (int ks = 0; ks < 4; ++ks) {
    short8 af[4], bfr[4];
#pragma unroll
    for (int mi = 0; mi < 4; ++mi) {
      const int row = wr * 64 + mi * 16 + (lane & 15);
      const int kc = ks * 4 + (lane >> 4);
      af[mi] = *(const short8*)&lA[row * 128 + (kc ^ (row & 7)) * 8];
    }
#pragma unroll
    for (int ni = 0; ni < 4; ++ni) {
      const int row = wc * 64 + ni * 16 + (lane & 15);
      const int kc = ks * 4 + (lane >> 4);
      bfr[ni] = *(const short8*)&lB[row * 128 + (kc ^ (row & 7)) * 8];
    }
#pragma unroll
    for (int mi = 0; mi < 4; ++mi)
#pragma unroll
      for (int ni = 0; ni < 4; ++ni)
        acc[mi][ni] = __builtin_amdgcn_mfma_f32_16x16x32_bf16(af[mi], bfr[ni], acc[mi][ni], 0, 0, 0);
  }

  __syncthreads();                       // all LDS fragment reads done
  f16* st = (f16*)smem;                  // staging, row stride 136 f16 (16B-aligned rows)
  const float scale = 1.0f / 128.0f;
  // rowpart slice: [bz][bx*2+wc][row]  (each wave's 64-col half-sum, no races)
  float* rp = rowpart + ((size_t)bz * 64 + bx * 2 + wc) * LL + by * 128;
#pragma unroll
  for (int mi = 0; mi < 4; ++mi) {
    float rs[4] = {0.f, 0.f, 0.f, 0.f};
    const int lr0 = wr * 64 + mi * 16 + (lane >> 4) * 4;
#pragma unroll
    for (int ni = 0; ni < 4; ++ni) {
      const int lc = wc * 64 + ni * 16 + (lane & 15);
      f32x4 a = acc[mi][ni];
#pragma unroll
      for (int r = 0; r < 4; ++r) {
        const f16 eh = (f16)__expf(a[r] * scale);
        st[(lr0 + r) * 136 + lc] = eh;
        rs[r] += (float)eh;
      }
    }
#pragma unroll
    for (int m = 1; m < 16; m <<= 1)
#pragma unroll
      for (int r = 0; r < 4; ++r) rs[r] += __shfl_xor(rs[r], m, 64);
    if ((lane & 15) == 0) {
#pragma unroll
      for (int r = 0; r < 4; ++r) rp[lr0 + r] = rs[r];
    }
  }
  __syncthreads();
  const size_t ebase = (size_t)bz * LL * SS + (size_t)(by * 128) * SS + (size_t)(bx * 128);
#pragma unroll
  for (int i = 0; i < 8; ++i) {
    const int c = i * 256 + tid;
    const int row = c >> 4, c16 = c & 15;
    f16x8 vv = *(const f16x8*)&st[row * 136 + c16 * 8];
    *(f16x8*)&E[ebase + (size_t)row * SS + c16 * 8] = vv;
  }
}

// ---------- column pass IT=1..3: (IT>1: row-dots -> eu), colpart[strip] = sum(eu*E)
//            IT>1 holds the 16x16 E sub-strip in registers: ONE E read total ----------
template <int IT>
__global__ __launch_bounds__(256, 2) void k_colpass(const f16* __restrict__ E,
                                                    const float* __restrict__ rowpart,
                                                    const float* __restrict__ evprev,
                                                    float* __restrict__ colpart,
                                                    float* __restrict__ eu3g,
                                                    float* __restrict__ scal,
                                                    const float* __restrict__ alpha_p) {
  __shared__ float lds_red[4][16];
  __shared__ float eu_lds[16];
  const int b = blockIdx.y, strip = blockIdx.x;
  const int t = threadIdx.x, lane = t & 63, wave = t >> 6;
  const float alpha = *alpha_p;
  const float EA = __expf(alpha), HE = 0.5f * __expf(-alpha);
  const float enorm = 1.0f / 8192.0f;
  const float EU1BIN = HE / 4097.0f;

  const f16* Eb = E + (size_t)b * LL * SS + (size_t)strip * 16 * SS;
  const int cA = t * 8, cB = 2048 + t * 8;
  float* co = colpart + ((size_t)b * NSTRIP + strip) * SS;

  if (IT == 1) {
    // eu1 for this strip from rowpart: 16 rows x 64 partials (wave 0 only)
    if (wave == 0) {
      const int r = lane & 15, g = lane >> 4;       // 4 groups x 16 rows
      float s = 0.f;
      const float* rp = rowpart + (size_t)b * 64 * LL + strip * 16 + r;
#pragma unroll
      for (int j = 0; j < 16; ++j) s += rp[(size_t)(g * 16 + j) * LL];
      s += __shfl_xor(s, 16, 64);
      s += __shfl_xor(s, 32, 64);
      float eu = 0.f;
      if (lane < 16) {
        eu = enorm / (s + EA);
        eu_lds[lane] = eu;
      }
      // sa1 partial (lanes 0-15 hold eu)
      float es = eu;
#pragma unroll
      for (int m = 1; m < 16; m <<= 1) es += __shfl_xor(es, m, 64);
      if (lane == 0) atomicAdd(&scal[b * 8 + 0], es);
    }
    __syncthreads();
    float eur[16];
#pragma unroll
    for (int r = 0; r < 16; ++r) eur[r] = eu_lds[r];
    float accA[8], accB[8];
#pragma unroll
    for (int e = 0; e < 8; ++e) { accA[e] = 0.f; accB[e] = 0.f; }
#pragma unroll
    for (int r = 0; r < 16; ++r) {
      const f16x8 hA = *(const f16x8*)(Eb + (size_t)r * SS + cA);
      const f16x8 hB = *(const f16x8*)(Eb + (size_t)r * SS + cB);
#pragma unroll
      for (int e = 0; e < 8; ++e) { accA[e] += eur[r] * (float)hA[e]; accB[e] += eur[r] * (float)hB[e]; }
    }
    *(f32x4*)&co[cA] = (f32x4){accA[0], accA[1], accA[2], accA[3]};
    *(f32x4*)&co[cA + 4] = (f32x4){accA[4], accA[5], accA[6], accA[7]};
    *(f32x4*)&co[cB] = (f32x4){accB[0], accB[1], accB[2], accB[3]};
    *(f32x4*)&co[cB + 4] = (f32x4){accB[4], accB[5], accB[6], accB[7]};
    return;
  }

  // ---- IT >= 2: bin-chain scalars ----
  const float sa1 = scal[b * 8 + 0];
  const float ev1bin = HE / (sa1 + EU1BIN);
  float btu;
  if (IT == 2) {
    btu = EA * ev1bin;
  } else {
    const float sev1 = scal[b * 8 + 1];
    const float eu2bin = HE / (sev1 + ev1bin);
    const float s2 = scal[b * 8 + 2];
    const float ev2bin = HE / (s2 + eu2bin);
    btu = EA * ev2bin;
  }
  const float* evb = evprev + (size_t)b * SS;
  const f32x4 evA0 = *(const f32x4*)&evb[cA];
  const f32x4 evA1 = *(const f32x4*)&evb[cA + 4];
  const f32x4 evB0 = *(const f32x4*)&evb[cB];
  const f32x4 evB1 = *(const f32x4*)&evb[cB + 4];

  // phase A: load E sub-strip into registers + per-thread partial row-dots
  f16x8 eAr[16], eBr[16];
  float partial[16];
#pragma unroll
  for (int r = 0; r < 16; ++r) {
    eAr[r] = *(const f16x8*)(Eb + (size_t)r * SS + cA);
    eBr[r] = *(const f16x8*)(Eb + (size_t)r * SS + cB);
    float d = 0.f;
#pragma unroll
    for (int e = 0; e < 4; ++e) d += (float)eAr[r][e] * evA0[e];
#pragma unroll
    for (int e = 0; e < 4; ++e) d += (float)eAr[r][4 + e] * evA1[e];
#pragma unroll
    for (int e = 0; e < 4; ++e) d += (float)eBr[r][e] * evB0[e];
#pragma unroll
    for (int e = 0; e < 4; ++e) d += (float)eBr[r][4 + e] * evB1[e];
    partial[r] = d;
  }

  // phase B: block reduction of 16 row-dots
#pragma unroll
  for (int m = 1; m < 64; m <<= 1)
#pragma unroll
    for (int r = 0; r < 16; ++r) partial[r] += __shfl_xor(partial[r], m, 64);
  if (lane == 0) {
#pragma unroll
    for (int r = 0; r < 16; ++r) lds_red[wave][r] = partial[r];
  }
  __syncthreads();
  if (t < 16) {
    const float rd = lds_red[0][t] + lds_red[1][t] + lds_red[2][t] + lds_red[3][t];
    const float eu = enorm / (rd + btu);
    eu_lds[t] = eu;
    if (IT == 3) eu3g[(size_t)b * LL + strip * 16 + t] = eu;
  }
  __syncthreads();
  if (IT == 2 && t == 0) {
    float s = 0.f;
#pragma unroll
    for (int r = 0; r < 16; ++r) s += eu_lds[r];
    atomicAdd(&scal[b * 8 + 2], s);
  }
  float eur[16];
#pragma unroll
  for (int r = 0; r < 16; ++r) eur[r] = eu_lds[r];

  // phase C: colpart from REGISTER-held E (no second memory read)
  float accA[8], accB[8];
#pragma unroll
  for (int e = 0; e < 8; ++e) { accA[e] = 0.f; accB[e] = 0.f; }
#pragma unroll
  for (int r = 0; r < 16; ++r) {
#pragma unroll
    for (int e = 0; e < 8; ++e) { accA[e] += eur[r] * (float)eAr[r][e]; accB[e] += eur[r] * (float)eBr[r][e]; }
  }
  *(f32x4*)&co[cA] = (f32x4){accA[0], accA[1], accA[2], accA[3]};
  *(f32x4*)&co[cA + 4] = (f32x4){accA[4], accA[5], accA[6], accA[7]};
  *(f32x4*)&co[cB] = (f32x4){accB[0], accB[1], accB[2], accB[3]};
  *(f32x4*)&co[cB + 4] = (f32x4){accB[4], accB[5], accB[6], accB[7]};
}

// ---------- reduce colpart -> ev_IT (+ sev atomic) ----------
template <int IT>
__global__ __launch_bounds__(256) void k_redcol(const float* __restrict__ colpart,
                                                float* __restrict__ evout,
                                                float* __restrict__ scal,
                                                const float* __restrict__ alpha_p) {
  __shared__ float red[4];
  const int b = blockIdx.y, t = threadIdx.x;
  const int c = blockIdx.x * 256 + t;
  const float alpha = *alpha_p;
  const float EA = __expf(alpha), HE = 0.5f * __expf(-alpha);
  const float enorm = 1.0f / 8192.0f;
  const float EU1BIN = HE / 4097.0f, BTV1 = 0.5f / 4097.0f;

  float s = 0.f;
  const float* cp = colpart + (size_t)b * NSTRIP * SS + c;
#pragma unroll 8
  for (int st = 0; st < NSTRIP; ++st) s += cp[(size_t)st * SS];

  float btv;
  if (IT == 1) {
    btv = BTV1;
  } else {
    const float sa1 = scal[b * 8 + 0];
    const float ev1bin = HE / (sa1 + EU1BIN);
    const float sev1 = scal[b * 8 + 1];
    const float eu2bin = HE / (sev1 + ev1bin);
    if (IT == 2) {
      btv = EA * eu2bin;
    } else {
      const float s2 = scal[b * 8 + 2];
      const float ev2bin = HE / (s2 + eu2bin);
      const float sev2 = scal[b * 8 + 3];
      const float eu3bin = HE / (sev2 + ev2bin);
      btv = EA * eu3bin;
    }
  }
  const float ev = enorm / (s + btv);
  evout[(size_t)b * SS + c] = ev;
  if (IT < 3) {
    const float bs = block_sum<4>(ev, red, t);
    if (t == 0) atomicAdd(&scal[b * 8 + (IT == 1 ? 1 : 3)], bs);
  }
}

// ---------- final: out = E * eu3[l] * ev3[s] * 8192 ----------
// Column-split: each block does 16 rows x 2048 cols -> 2048 blocks, ~40 VGPR.
__global__ __launch_bounds__(256) void k_finalize(const f16* __restrict__ E,
                                                  float* __restrict__ out,
                                                  const float* __restrict__ eu3g,
                                                  const float* __restrict__ ev3g) {
  __shared__ float eu_s[16];
  const int b = blockIdx.y;
  const int rb = blockIdx.x >> 1, half = blockIdx.x & 1;
  const int t = threadIdx.x, lane = t & 63, wave = t >> 6;
  if (t < 16) eu_s[t] = eu3g[(size_t)b * LL + rb * 16 + t] * 8192.0f;

  const float* evb = ev3g + (size_t)b * SS + half * 2048;
  f32x4 evr[8];
#pragma unroll
  for (int it = 0; it < 4; ++it) {
    const int base = (it * 64 + lane) * 8;
    evr[it * 2] = *(const f32x4*)&evb[base];
    evr[it * 2 + 1] = *(const f32x4*)&evb[base + 4];
  }
  __syncthreads();

  const size_t rbase = (size_t)b * LL * SS + (size_t)(rb * 16) * SS + half * 2048;
#pragma unroll
  for (int rr = 0; rr < 4; ++rr) {
    const int rloc = wave * 4 + rr;
    const float a = eu_s[rloc];
    const f16x8* rowp = (const f16x8*)(E + rbase + (size_t)rloc * SS);
    f32x4* orow = (f32x4*)(out + rbase + (size_t)rloc * SS);
#pragma unroll
    for (int it = 0; it < 4; ++it) {
      const f16x8 h = rowp[it * 64 + lane];
      f32x4 o0, o1;
#pragma unroll
      for (int e = 0; e < 4; ++e) o0[e] = (float)h[e] * a * evr[it * 2][e];
#pragma unroll
      for (int e = 0; e < 4; ++e) o1[e] = (float)h[4 + e] * a * evr[it * 2 + 1][e];
      orow[2 * (it * 64 + lane)] = o0;
      orow[2 * (it * 64 + lane) + 1] = o1;
    }
  }
}

// ---------- launch ----------
extern "C" void kernel_launch(void* const* d_in, const int* in_sizes, int n_in,
                              void* d_out, int out_size, void* d_ws, size_t ws_size,
                              hipStream_t stream) {
  const float* f0 = (const float*)d_in[0];
  const float* f1 = (const float*)d_in[1];
  const float* alpha_p = (const float*)d_in[2];
  float* out = (float*)d_out;

  char* ws = (char*)d_ws;
  size_t off = (size_t)NB * LL * SS * 2;                    // E: 128 MiB
  f16* E = (f16*)ws;
  u16* b0 = (u16*)(ws + off);      off += (size_t)NB * LL * CC * 2;
  u16* b1 = (u16*)(ws + off);      off += (size_t)NB * SS * CC * 2;
  float* rowpart = (float*)(ws + off); off += (size_t)NB * 64 * LL * 4;     // 4 MiB
  float* colpart = (float*)(ws + off); off += (size_t)NB * NSTRIP * SS * 4; // 16 MiB
  float* eu3g = (float*)(ws + off);    off += (size_t)NB * LL * 4;
  float* ev1g = (float*)(ws + off);    off += (size_t)NB * SS * 4;
  float* ev2g = (float*)(ws + off);    off += (size_t)NB * SS * 4;
  float* ev3g = (float*)(ws + off);    off += (size_t)NB * SS * 4;
  float* scal = (float*)(ws + off);    off += 256;

  k_convert<<<2048, 256, 0, stream>>>(f0, f1, b0, b1, scal);
  k_gemm<<<dim3(SS / 128, LL / 128, NB), 256, 0, stream>>>(b0, b1, E, rowpart);

  k_colpass<1><<<dim3(NSTRIP, NB), 256, 0, stream>>>(E, rowpart, nullptr, colpart, eu3g, scal, alpha_p);
  k_redcol<1><<<dim3(16, NB), 256, 0, stream>>>(colpart, ev1g, scal, alpha_p);

  k_colpass<2><<<dim3(NSTRIP, NB), 256, 0, stream>>>(E, rowpart, ev1g, colpart, eu3g, scal, alpha_p);
  k_redcol<2><<<dim3(16, NB), 256, 0, stream>>>(colpart, ev2g, scal, alpha_p);

  k_colpass<3><<<dim3(NSTRIP, NB), 256, 0, stream>>>(E, rowpart, ev2g, colpart, eu3g, scal, alpha_p);
  k_redcol<3><<<dim3(16, NB), 256, 0, stream>>>(colpart, ev3g, scal, alpha_p);

  k_finalize<<<dim3(LL / 16 * 2, NB), 256, 0, stream>>>(E, out, eu3g, ev3g);
}